// Round 27
// baseline (289.130 us; speedup 1.0000x reference)
//
#include <hip/hip_runtime.h>
#include <hip/hip_bf16.h>
#include <stdint.h>

typedef __hip_bfloat16 bf16;
typedef __attribute__((ext_vector_type(8))) short short8;
typedef __attribute__((ext_vector_type(4))) float f32x4;

#define D_MODEL 2048
#define NHEADS 16
#define NKV 4
#define HD 128
#define BATCH 2
#define SEQ 2048
#define NTOK (BATCH*SEQ)
#define QKN 2560                       // q+k row stride (V split out)
#define QSCALE 0.08838834764831845f
#define QSCALE_L2E (0.08838834764831845f * 1.4426950408889634f)

// ---------------- trig table: [s][i] -> (cos, sin), double precision ----------------
__global__ __launch_bounds__(256) void trig_kernel(float2* __restrict__ tab) {
    int idx = blockIdx.x * 256 + threadIdx.x;       // < 2048*64
    int s = idx >> 6, i = idx & 63;
    double inv_freq = pow(10000.0, -(double)i / 64.0);
    double sn, cs;
    sincos((double)s * inv_freq, &sn, &cs);
    tab[idx] = make_float2((float)cs, (float)sn);
}

// ---------------- vectorized convert: fp32 -> bf16 (8 el/thread) ----------------
__global__ __launch_bounds__(256) void conv8(const float* __restrict__ in,
                                             bf16* __restrict__ out, int n8) {
    int idx = blockIdx.x * 256 + threadIdx.x;
    if (idx >= n8) return;
    const float4* p = (const float4*)(in + (size_t)idx * 8);
    float4 a = p[0], b = p[1];
    union { short8 v; bf16 e[8]; } u;
    u.e[0] = __float2bfloat16(a.x); u.e[1] = __float2bfloat16(a.y);
    u.e[2] = __float2bfloat16(a.z); u.e[3] = __float2bfloat16(a.w);
    u.e[4] = __float2bfloat16(b.x); u.e[5] = __float2bfloat16(b.y);
    u.e[6] = __float2bfloat16(b.z); u.e[7] = __float2bfloat16(b.w);
    *(short8*)(out + (size_t)idx * 8) = u.v;
}

// ------- convert-transpose: fp32 [K][N] -> bf16 [N][K]; TILE_LD=68 (272B rows, aligned) -------
#define TILE_LD 68
__global__ __launch_bounds__(256) void ct64(const float* __restrict__ in,
                                            bf16* __restrict__ out, int K, int N) {
    __shared__ float tile[64 * TILE_LD];
    int n0 = blockIdx.x * 64, k0 = blockIdx.y * 64;
    int t = threadIdx.x;
#pragma unroll
    for (int i = 0; i < 4; ++i) {
        int idx = t + 256 * i;
        int r = idx >> 4;
        int c4 = (idx & 15) * 4;
        *(float4*)&tile[r * TILE_LD + c4] = *(const float4*)(in + (size_t)(k0 + r) * N + n0 + c4);
    }
    __syncthreads();
#pragma unroll
    for (int i = 0; i < 2; ++i) {
        int idx = t + 256 * i;
        int n = idx >> 3;
        int kc = (idx & 7) * 8;
        union { short8 v; bf16 e[8]; } u;
#pragma unroll
        for (int j = 0; j < 8; ++j) u.e[j] = __float2bfloat16(tile[(kc + j) * TILE_LD + n]);
        *(short8*)(out + (size_t)(n0 + n) * K + k0 + kc) = u.v;
    }
}

// ------- GEMM BK=32 swizzled (R26-proven body), fused-RoPE epilogue, N=2560 (q+k) -------
__global__ __launch_bounds__(256) void gemm_qk(const bf16* __restrict__ A,
                                               const bf16* __restrict__ Bt,
                                               bf16* __restrict__ C, int M, int N, int K,
                                               const float2* __restrict__ trig) {
    __shared__ bf16 As[128 * 32];
    __shared__ bf16 Bs[128 * 32];
    const int GX = gridDim.x;
    const int nwg = GX * gridDim.y;
    const int lin = blockIdx.y * GX + blockIdx.x;
    const int swz = (lin & 7) * (nwg >> 3) + (lin >> 3);
    const int m0 = (swz / GX) * 128, n0 = (swz % GX) * 128;
    const int tid = threadIdx.x;
    const int wave = tid >> 6, lane = tid & 63;
    const int wr = wave >> 1, wc = wave & 1;
    const int l15 = lane & 15, g = lane >> 4;
    const int srow = lane >> 2;
    const int sk8 = 8 * ((lane & 3) ^ ((srow >> 1) & 3));
    const int rsw = ((l15 >> 1) & 3) << 3;
    f32x4 acc[4][4] = {};

    for (int k0 = 0; k0 < K; k0 += 32) {
        __syncthreads();
#pragma unroll
        for (int i = 0; i < 2; ++i) {
            int chunk = wave * 2 + i;
            const bf16* ga = A + (size_t)(m0 + chunk * 16 + srow) * K + k0 + sk8;
            bf16* la = As + chunk * 512 + lane * 8;
            __builtin_amdgcn_global_load_lds((const __attribute__((address_space(1))) void*)ga,
                                             (__attribute__((address_space(3))) void*)la, 16, 0, 0);
            const bf16* gb = Bt + (size_t)(n0 + chunk * 16 + srow) * K + k0 + sk8;
            bf16* lb = Bs + chunk * 512 + lane * 8;
            __builtin_amdgcn_global_load_lds((const __attribute__((address_space(1))) void*)gb,
                                             (__attribute__((address_space(3))) void*)lb, 16, 0, 0);
        }
        __syncthreads();
        short8 af[4], bfr[4];
#pragma unroll
        for (int mi = 0; mi < 4; ++mi)
            af[mi] = *(const short8*)&As[(wr * 64 + mi * 16 + l15) * 32 + ((g * 8) ^ rsw)];
#pragma unroll
        for (int ni = 0; ni < 4; ++ni)
            bfr[ni] = *(const short8*)&Bs[(wc * 64 + ni * 16 + l15) * 32 + ((g * 8) ^ rsw)];
#pragma unroll
        for (int mi = 0; mi < 4; ++mi)
#pragma unroll
            for (int ni = 0; ni < 4; ++ni)
                acc[mi][ni] = __builtin_amdgcn_mfma_f32_16x16x32_bf16(af[mi], bfr[ni], acc[mi][ni], 0, 0, 0);
    }
#pragma unroll
    for (int mi = 0; mi < 4; ++mi)
#pragma unroll
        for (int ni = 0; ni < 4; ++ni) {
            int row = m0 + wr * 64 + mi * 16 + g * 4;
            int col = n0 + wc * 64 + ni * 16 + l15;
#pragma unroll
            for (int r = 0; r < 4; ++r) {
                float v = acc[mi][ni][r];
                float partner = __shfl_xor(v, 1);   // pair lane (col^1)
                int s = (row + r) & (SEQ - 1);
                int i2 = (col & 127) >> 1;
                float2 t = trig[s * 64 + i2];
                v = (col & 1) ? (v * t.x + partner * t.y)
                              : (v * t.x - partner * t.y);
                if (col < 2048) v *= QSCALE_L2E;
                C[(size_t)(row + r) * N + col] = __float2bfloat16(v);
            }
        }
}

// ------- GEMM BK=32 swizzled, V projection with DIRECT transposed store into vT -------
// vT[(b*512 + col)][s]; rows r..r+3 are consecutive s -> one 8B ushort4 store per lane.
__global__ __launch_bounds__(256) void gemm_vt(const bf16* __restrict__ A,
                                               const bf16* __restrict__ Bt,
                                               bf16* __restrict__ vT, int M, int N, int K) {
    __shared__ bf16 As[128 * 32];
    __shared__ bf16 Bs[128 * 32];
    const int GX = gridDim.x;
    const int nwg = GX * gridDim.y;
    const int lin = blockIdx.y * GX + blockIdx.x;
    const int swz = (lin & 7) * (nwg >> 3) + (lin >> 3);
    const int m0 = (swz / GX) * 128, n0 = (swz % GX) * 128;
    const int tid = threadIdx.x;
    const int wave = tid >> 6, lane = tid & 63;
    const int wr = wave >> 1, wc = wave & 1;
    const int l15 = lane & 15, g = lane >> 4;
    const int srow = lane >> 2;
    const int sk8 = 8 * ((lane & 3) ^ ((srow >> 1) & 3));
    const int rsw = ((l15 >> 1) & 3) << 3;
    f32x4 acc[4][4] = {};

    for (int k0 = 0; k0 < K; k0 += 32) {
        __syncthreads();
#pragma unroll
        for (int i = 0; i < 2; ++i) {
            int chunk = wave * 2 + i;
            const bf16* ga = A + (size_t)(m0 + chunk * 16 + srow) * K + k0 + sk8;
            bf16* la = As + chunk * 512 + lane * 8;
            __builtin_amdgcn_global_load_lds((const __attribute__((address_space(1))) void*)ga,
                                             (__attribute__((address_space(3))) void*)la, 16, 0, 0);
            const bf16* gb = Bt + (size_t)(n0 + chunk * 16 + srow) * K + k0 + sk8;
            bf16* lb = Bs + chunk * 512 + lane * 8;
            __builtin_amdgcn_global_load_lds((const __attribute__((address_space(1))) void*)gb,
                                             (__attribute__((address_space(3))) void*)lb, 16, 0, 0);
        }
        __syncthreads();
        short8 af[4], bfr[4];
#pragma unroll
        for (int mi = 0; mi < 4; ++mi)
            af[mi] = *(const short8*)&As[(wr * 64 + mi * 16 + l15) * 32 + ((g * 8) ^ rsw)];
#pragma unroll
        for (int ni = 0; ni < 4; ++ni)
            bfr[ni] = *(const short8*)&Bs[(wc * 64 + ni * 16 + l15) * 32 + ((g * 8) ^ rsw)];
#pragma unroll
        for (int mi = 0; mi < 4; ++mi)
#pragma unroll
            for (int ni = 0; ni < 4; ++ni)
                acc[mi][ni] = __builtin_amdgcn_mfma_f32_16x16x32_bf16(af[mi], bfr[ni], acc[mi][ni], 0, 0, 0);
    }
#pragma unroll
    for (int mi = 0; mi < 4; ++mi)
#pragma unroll
        for (int ni = 0; ni < 4; ++ni) {
            int row = m0 + wr * 64 + mi * 16 + g * 4;
            int col = n0 + wc * 64 + ni * 16 + l15;    // vd 0..511
            int bb = row >> 11, ss = row & 2047;
            union { ushort4 u4; bf16 e[4]; } pk;
#pragma unroll
            for (int r = 0; r < 4; ++r) pk.e[r] = __float2bfloat16(acc[mi][ni][r]);
            *(ushort4*)(vT + (size_t)(bb * 512 + col) * 2048 + ss) = pk.u4;
        }
}

// ------- GEMM BK=64 (gemm2, R21/R26-proven) -------
template <typename OutT>
__global__ __launch_bounds__(256) void gemm_bt64(const bf16* __restrict__ A,
                                                 const bf16* __restrict__ Bt,
                                                 OutT* __restrict__ C, int M, int N, int K) {
    __shared__ bf16 As[128 * 64];
    __shared__ bf16 Bs[128 * 64];
    const int GX = gridDim.x;
    const int nwg = GX * gridDim.y;
    const int lin = blockIdx.y * GX + blockIdx.x;
    const int swz = (lin & 7) * (nwg >> 3) + (lin >> 3);
    const int m0 = (swz / GX) * 128, n0 = (swz % GX) * 128;
    const int tid = threadIdx.x;
    const int wave = tid >> 6, lane = tid & 63;
    const int wr = wave >> 1, wc = wave & 1;
    const int l15 = lane & 15, g = lane >> 4;
    f32x4 acc[4][4] = {};

    const bf16* ga[4];
    const bf16* gb[4];
#pragma unroll
    for (int i = 0; i < 4; ++i) {
        int cidx = tid + 256 * i;
        int r = cidx >> 3, j = cidx & 7;
        int sc = 8 * (j ^ (r & 7));
        ga[i] = A + (size_t)(m0 + r) * K + sc;
        gb[i] = Bt + (size_t)(n0 + r) * K + sc;
    }

    for (int k0 = 0; k0 < K; k0 += 64) {
        __syncthreads();
#pragma unroll
        for (int i = 0; i < 4; ++i) {
            int cidx = tid + 256 * i;
            __builtin_amdgcn_global_load_lds(
                (const __attribute__((address_space(1))) void*)ga[i],
                (__attribute__((address_space(3))) void*)(As + cidx * 8), 16, 0, 0);
            __builtin_amdgcn_global_load_lds(
                (const __attribute__((address_space(1))) void*)gb[i],
                (__attribute__((address_space(3))) void*)(Bs + cidx * 8), 16, 0, 0);
            ga[i] += 64;
            gb[i] += 64;
        }
        __syncthreads();
#pragma unroll
        for (int kk = 0; kk < 2; ++kk) {
            short8 af[4], bfr[4];
#pragma unroll
            for (int mi = 0; mi < 4; ++mi) {
                int row = wr * 64 + mi * 16 + l15;
                af[mi] = *(const short8*)&As[row * 64 + ((kk * 32 + g * 8) ^ ((row & 7) << 3))];
            }
#pragma unroll
            for (int ni = 0; ni < 4; ++ni) {
                int row = wc * 64 + ni * 16 + l15;
                bfr[ni] = *(const short8*)&Bs[row * 64 + ((kk * 32 + g * 8) ^ ((row & 7) << 3))];
            }
#pragma unroll
            for (int mi = 0; mi < 4; ++mi)
#pragma unroll
                for (int ni = 0; ni < 4; ++ni)
                    acc[mi][ni] = __builtin_amdgcn_mfma_f32_16x16x32_bf16(af[mi], bfr[ni], acc[mi][ni], 0, 0, 0);
        }
    }
#pragma unroll
    for (int mi = 0; mi < 4; ++mi)
#pragma unroll
        for (int ni = 0; ni < 4; ++ni) {
            int row = m0 + wr * 64 + mi * 16 + g * 4;
            int col = n0 + wc * 64 + ni * 16 + l15;
#pragma unroll
            for (int r = 0; r < 4; ++r) {
                float v = acc[mi][ni][r];
                if constexpr (__is_same(OutT, float))
                    C[(size_t)(row + r) * N + col] = v;
                else
                    C[(size_t)(row + r) * N + col] = __float2bfloat16(v);
            }
        }
}

// ---- MFMA flash attention v10 (R25-proven math), qk stride QKN=2560 ----
#define PL_LD 72
__global__ __launch_bounds__(256) void attn10(const bf16* __restrict__ qkv,
                                              const bf16* __restrict__ vT,
                                              bf16* __restrict__ y) {
    const int bx = blockIdx.x, h = blockIdx.y, b = blockIdx.z;
    const int kvh = h >> 2;
    const int tid = threadIdx.x, wave = tid >> 6, lane = tid & 63;
    const int l15 = lane & 15, g = lane >> 4;
    __shared__ bf16 Ks[64 * 128];
    __shared__ bf16 Vt[128 * 64];
    __shared__ bf16 Pl[4][16 * PL_LD];
    bf16* plw = Pl[0] + wave * 16 * PL_LD;

    for (int half = 0; half < 2; ++half) {
        const int qt = half ? (31 - bx) : bx;
        const int qrow0 = qt * 64 + wave * 16;
        short8 qf[4];
        {
            const bf16* qp = qkv + (size_t)(b * SEQ + qrow0 + l15) * QKN + h * HD + g * 8;
#pragma unroll
            for (int c = 0; c < 4; ++c) qf[c] = *(const short8*)(qp + c * 32);
        }
        f32x4 acc[8] = {};
        float m_[4], lsum[4];
#pragma unroll
        for (int r = 0; r < 4; ++r) { m_[r] = -3.0e38f; lsum[r] = 0.f; }

        const bf16* gk[4];
        const bf16* gv[4];
#pragma unroll
        for (int i = 0; i < 4; ++i) {
            int cidx = tid + 256 * i;
            int key = cidx >> 4, j = cidx & 15;
            gk[i] = qkv + (size_t)(b * SEQ + key) * QKN + 2048 + kvh * HD + 8 * (j ^ (key & 7));
            int d = cidx >> 3, j2 = cidx & 7;
            gv[i] = vT + (size_t)(b * 512 + kvh * HD + d) * 2048 + 8 * (j2 ^ (d & 7));
        }

        const int diag_kv0 = qt * 64;
        for (int kv0 = 0; kv0 <= diag_kv0; kv0 += 64) {
#pragma unroll
            for (int i = 0; i < 4; ++i) {
                int cidx = tid + 256 * i;
                __builtin_amdgcn_global_load_lds(
                    (const __attribute__((address_space(1))) void*)gk[i],
                    (__attribute__((address_space(3))) void*)(Ks + cidx * 8), 16, 0, 0);
                __builtin_amdgcn_global_load_lds(
                    (const __attribute__((address_space(1))) void*)gv[i],
                    (__attribute__((address_space(3))) void*)(Vt + cidx * 8), 16, 0, 0);
                gk[i] += 64 * QKN;
                gv[i] += 64;
            }
            __syncthreads();

            f32x4 sc[4];
            __builtin_amdgcn_s_setprio(1);
#pragma unroll
            for (int ct = 0; ct < 4; ++ct) {
                sc[ct] = (f32x4){0.f, 0.f, 0.f, 0.f};
                int key = ct * 16 + l15;
                int ksw = (key & 7) << 3;
#pragma unroll
                for (int c = 0; c < 4; ++c) {
                    short8 kf = *(const short8*)&Ks[key * 128 + ((c * 32 + g * 8) ^ ksw)];
                    sc[ct] = __builtin_amdgcn_mfma_f32_16x16x32_bf16(qf[c], kf, sc[ct], 0, 0, 0);
                }
            }
            __builtin_amdgcn_s_setprio(0);
            if (kv0 == diag_kv0) {
                int qbase = qrow0 + g * 4;
#pragma unroll
                for (int ct = 0; ct < 4; ++ct) {
                    int key = kv0 + ct * 16 + l15;
#pragma unroll
                    for (int r = 0; r < 4; ++r)
                        if (key > qbase + r) sc[ct][r] = -3.0e38f;
                }
            }
#pragma unroll
            for (int r = 0; r < 4; ++r) {
                float pmax = fmaxf(fmaxf(sc[0][r], sc[1][r]), fmaxf(sc[2][r], sc[3][r]));
                if (__any(pmax > m_[r] + 8.0f)) {
                    float mx = pmax;
#pragma unroll
                    for (int o = 1; o < 16; o <<= 1) mx = fmaxf(mx, __shfl_xor(mx, o));
                    float mn = fmaxf(m_[r], mx);
                    float alpha = exp2f(m_[r] - mn);
                    m_[r] = mn;
                    lsum[r] *= alpha;
#pragma unroll
                    for (int nt = 0; nt < 8; ++nt) acc[nt][r] *= alpha;
                }
                float p0 = exp2f(sc[0][r] - m_[r]);
                float p1 = exp2f(sc[1][r] - m_[r]);
                float p2 = exp2f(sc[2][r] - m_[r]);
                float p3 = exp2f(sc[3][r] - m_[r]);
                int row = g * 4 + r;
                plw[row * PL_LD + l15]      = __float2bfloat16(p0);
                plw[row * PL_LD + 16 + l15] = __float2bfloat16(p1);
                plw[row * PL_LD + 32 + l15] = __float2bfloat16(p2);
                plw[row * PL_LD + 48 + l15] = __float2bfloat16(p3);
                lsum[r] += (p0 + p1) + (p2 + p3);
            }
            short8 pf0 = *(const short8*)&plw[l15 * PL_LD + g * 8];
            short8 pf1 = *(const short8*)&plw[l15 * PL_LD + 32 + g * 8];
            __builtin_amdgcn_s_setprio(1);
#pragma unroll
            for (int nt = 0; nt < 8; ++nt) {
                int d = nt * 16 + l15;
                int dsw = (d & 7) << 3;
                short8 vf0 = *(const short8*)&Vt[d * 64 + ((g * 8) ^ dsw)];
                short8 vf1 = *(const short8*)&Vt[d * 64 + ((32 + g * 8) ^ dsw)];
                acc[nt] = __builtin_amdgcn_mfma_f32_16x16x32_bf16(pf0, vf0, acc[nt], 0, 0, 0);
                acc[nt] = __builtin_amdgcn_mfma_f32_16x16x32_bf16(pf1, vf1, acc[nt], 0, 0, 0);
            }
            __builtin_amdgcn_s_setprio(0);
            __syncthreads();
        }
        float linv[4];
#pragma unroll
        for (int r = 0; r < 4; ++r) {
            float ls = lsum[r];
#pragma unroll
            for (int o = 1; o < 16; o <<= 1) ls += __shfl_xor(ls, o);
            linv[r] = 1.0f / ls;
        }
        int qrow = qrow0 + g * 4;
#pragma unroll
        for (int nt = 0; nt < 8; ++nt) {
            int d = nt * 16 + l15;
#pragma unroll
            for (int r = 0; r < 4; ++r)
                y[(size_t)(b * SEQ + qrow + r) * D_MODEL + h * HD + d] =
                    __float2bfloat16(acc[nt][r] * linv[r]);
        }
        __syncthreads();
    }
}

extern "C" void kernel_launch(void* const* d_in, const int* in_sizes, int n_in,
                              void* d_out, int out_size, void* d_ws, size_t ws_size,
                              hipStream_t stream) {
    const float* x  = (const float*)d_in[0];
    const float* wq = (const float*)d_in[1];
    const float* wk = (const float*)d_in[2];
    const float* wv = (const float*)d_in[3];
    const float* wo = (const float*)d_in[4];

    // ws (50.33MB, proven): qkvb bf16 [4096][2560] @0 (10.49M el) | ybb [4096][2048] @10.49M
    //   | woT [2048][2048] @18.87M | vT [1024][2048] @23.07M  (sum = 25.17M el exactly)
    // d_out (33.55MB scratch): xb bf16 @0 (8.39M) + wqkT [2560][2048] (5.24M) +
    //   wvT [512][2048] (1.05M) + trig float2 (0.52M f2) = 15.73M bf16-el; final output overwrites.
    bf16*   qkvb = (bf16*)d_ws;
    bf16*   ybb  = (bf16*)d_ws + (size_t)NTOK * QKN;
    bf16*   woT  = (bf16*)d_ws + (size_t)NTOK * QKN + (size_t)NTOK * D_MODEL;
    bf16*   vT   = woT + (size_t)D_MODEL * D_MODEL;
    bf16*   xb   = (bf16*)d_out;
    bf16*   wqkT = (bf16*)d_out + (size_t)NTOK * D_MODEL;
    bf16*   wvT  = wqkT + (size_t)QKN * D_MODEL;
    float2* trig = (float2*)(wvT + (size_t)512 * D_MODEL);
    float*  outf = (float*)d_out;

    // phase 1: converts + trig table
    conv8<<<dim3(NTOK * D_MODEL / (256 * 8)), 256, 0, stream>>>(x, xb, NTOK * D_MODEL / 8);
    ct64<<<dim3(32, 32), 256, 0, stream>>>(wq, wqkT, 2048, 2048);
    ct64<<<dim3(8, 32), 256, 0, stream>>>(wk, wqkT + (size_t)2048 * 2048, 2048, 512);
    ct64<<<dim3(8, 32), 256, 0, stream>>>(wv, wvT, 2048, 512);
    ct64<<<dim3(32, 32), 256, 0, stream>>>(wo, woT, 2048, 2048);
    trig_kernel<<<dim3(SEQ * 64 / 256), 256, 0, stream>>>(trig);

    // phase 2: q+k projection with fused RoPE -> qkvb; V projection -> vT (transposed direct)
    gemm_qk<<<dim3(QKN / 128, NTOK / 128), 256, 0, stream>>>(
        xb, wqkT, qkvb, NTOK, QKN, D_MODEL, trig);
    gemm_vt<<<dim3(512 / 128, NTOK / 128), 256, 0, stream>>>(
        xb, wvT, vT, NTOK, 512, D_MODEL);

    // phase 3: attention -> ybb (ws)
    attn10<<<dim3(16, NHEADS, BATCH), 256, 0, stream>>>(qkvb, vT, ybb);

    // phase 4: out-projection (BK=64) -> fp32 directly into d_out
    gemm_bt64<float><<<dim3(D_MODEL / 128, NTOK / 128), 256, 0, stream>>>(
        ybb, woT, outf, NTOK, D_MODEL, D_MODEL);
}

// Round 28
// 239.554 us; speedup vs baseline: 1.2070x; 1.2070x over previous
//
#include <hip/hip_runtime.h>
#include <hip/hip_bf16.h>
#include <stdint.h>

typedef __hip_bfloat16 bf16;
typedef __attribute__((ext_vector_type(8))) short short8;
typedef __attribute__((ext_vector_type(4))) float f32x4;

#define D_MODEL 2048
#define NHEADS 16
#define NKV 4
#define HD 128
#define BATCH 2
#define SEQ 2048
#define NTOK (BATCH*SEQ)
#define QKV_N 3072
#define QSCALE 0.08838834764831845f
#define QSCALE_L2E (0.08838834764831845f * 1.4426950408889634f)

// ---------------- trig table: [s][i] -> (cos, sin), double precision ----------------
__global__ __launch_bounds__(256) void trig_kernel(float2* __restrict__ tab) {
    int idx = blockIdx.x * 256 + threadIdx.x;       // < 2048*64
    int s = idx >> 6, i = idx & 63;
    double inv_freq = pow(10000.0, -(double)i / 64.0);
    double sn, cs;
    sincos((double)s * inv_freq, &sn, &cs);
    tab[idx] = make_float2((float)cs, (float)sn);
}

// ---------------- vectorized convert: fp32 -> bf16 (8 el/thread) ----------------
__global__ __launch_bounds__(256) void conv8(const float* __restrict__ in,
                                             bf16* __restrict__ out, int n8) {
    int idx = blockIdx.x * 256 + threadIdx.x;
    if (idx >= n8) return;
    const float4* p = (const float4*)(in + (size_t)idx * 8);
    float4 a = p[0], b = p[1];
    union { short8 v; bf16 e[8]; } u;
    u.e[0] = __float2bfloat16(a.x); u.e[1] = __float2bfloat16(a.y);
    u.e[2] = __float2bfloat16(a.z); u.e[3] = __float2bfloat16(a.w);
    u.e[4] = __float2bfloat16(b.x); u.e[5] = __float2bfloat16(b.y);
    u.e[6] = __float2bfloat16(b.z); u.e[7] = __float2bfloat16(b.w);
    *(short8*)(out + (size_t)idx * 8) = u.v;
}

// ------- convert-transpose: fp32 [K][N] -> bf16 [N][K]; TILE_LD=68 (272B rows, aligned) -------
#define TILE_LD 68
__global__ __launch_bounds__(256) void ct64(const float* __restrict__ in,
                                            bf16* __restrict__ out, int K, int N) {
    __shared__ float tile[64 * TILE_LD];
    int n0 = blockIdx.x * 64, k0 = blockIdx.y * 64;
    int t = threadIdx.x;
#pragma unroll
    for (int i = 0; i < 4; ++i) {
        int idx = t + 256 * i;
        int r = idx >> 4;
        int c4 = (idx & 15) * 4;
        *(float4*)&tile[r * TILE_LD + c4] = *(const float4*)(in + (size_t)(k0 + r) * N + n0 + c4);
    }
    __syncthreads();
#pragma unroll
    for (int i = 0; i < 2; ++i) {
        int idx = t + 256 * i;
        int n = idx >> 3;
        int kc = (idx & 7) * 8;
        union { short8 v; bf16 e[8]; } u;
#pragma unroll
        for (int j = 0; j < 8; ++j) u.e[j] = __float2bfloat16(tile[(kc + j) * TILE_LD + n]);
        *(short8*)(out + (size_t)(n0 + n) * K + k0 + kc) = u.v;
    }
}

// ---- V^T: qkvb v-cols [token][2560+vd] -> vT [(b*512+vd)][s] (bf16, 64x64 LDS tiles) ----
__global__ __launch_bounds__(256) void vt64(const bf16* __restrict__ qkvb,
                                            bf16* __restrict__ vT) {
    __shared__ bf16 tile[64 * 72];
    int vd0 = blockIdx.x * 64, s0 = blockIdx.y * 64, b = blockIdx.z;
    int t = threadIdx.x;
#pragma unroll
    for (int i = 0; i < 2; ++i) {
        int idx = t + 256 * i;
        int r = idx >> 3;
        int c8 = (idx & 7) * 8;
        *(int4*)&tile[r * 72 + c8] =
            *(const int4*)(qkvb + (size_t)(b * SEQ + s0 + r) * QKV_N + 2560 + vd0 + c8);
    }
    __syncthreads();
#pragma unroll
    for (int i = 0; i < 2; ++i) {
        int idx = t + 256 * i;
        int vd = idx >> 3;
        int s8 = (idx & 7) * 8;
        union { short8 v; bf16 e[8]; } u;
#pragma unroll
        for (int j = 0; j < 8; ++j) u.e[j] = tile[(s8 + j) * 72 + vd];
        *(short8*)(vT + (size_t)(b * 512 + vd0 + vd) * 2048 + s0 + s8) = u.v;
    }
}

// ------- GEMM BK=32 + LDS XOR swizzle (2-way banks): m97 structure, fused-RoPE epilogue -------
template <typename OutT, bool ROPE>
__global__ __launch_bounds__(256) void gemm_bt32(const bf16* __restrict__ A,
                                                 const bf16* __restrict__ Bt,
                                                 OutT* __restrict__ C, int M, int N, int K,
                                                 const float2* __restrict__ trig) {
    __shared__ bf16 As[128 * 32];
    __shared__ bf16 Bs[128 * 32];
    const int GX = gridDim.x;
    const int nwg = GX * gridDim.y;
    const int lin = blockIdx.y * GX + blockIdx.x;
    const int swz = (lin & 7) * (nwg >> 3) + (lin >> 3);
    const int m0 = (swz / GX) * 128, n0 = (swz % GX) * 128;
    const int tid = threadIdx.x;
    const int wave = tid >> 6, lane = tid & 63;
    const int wr = wave >> 1, wc = wave & 1;
    const int l15 = lane & 15, g = lane >> 4;
    const int srow = lane >> 2;
    const int sk8 = 8 * ((lane & 3) ^ ((srow >> 1) & 3));
    const int rsw = ((l15 >> 1) & 3) << 3;
    f32x4 acc[4][4] = {};

    for (int k0 = 0; k0 < K; k0 += 32) {
        __syncthreads();
#pragma unroll
        for (int i = 0; i < 2; ++i) {
            int chunk = wave * 2 + i;
            const bf16* ga = A + (size_t)(m0 + chunk * 16 + srow) * K + k0 + sk8;
            bf16* la = As + chunk * 512 + lane * 8;
            __builtin_amdgcn_global_load_lds((const __attribute__((address_space(1))) void*)ga,
                                             (__attribute__((address_space(3))) void*)la, 16, 0, 0);
            const bf16* gb = Bt + (size_t)(n0 + chunk * 16 + srow) * K + k0 + sk8;
            bf16* lb = Bs + chunk * 512 + lane * 8;
            __builtin_amdgcn_global_load_lds((const __attribute__((address_space(1))) void*)gb,
                                             (__attribute__((address_space(3))) void*)lb, 16, 0, 0);
        }
        __syncthreads();
        short8 af[4], bfr[4];
#pragma unroll
        for (int mi = 0; mi < 4; ++mi)
            af[mi] = *(const short8*)&As[(wr * 64 + mi * 16 + l15) * 32 + ((g * 8) ^ rsw)];
#pragma unroll
        for (int ni = 0; ni < 4; ++ni)
            bfr[ni] = *(const short8*)&Bs[(wc * 64 + ni * 16 + l15) * 32 + ((g * 8) ^ rsw)];
#pragma unroll
        for (int mi = 0; mi < 4; ++mi)
#pragma unroll
            for (int ni = 0; ni < 4; ++ni)
                acc[mi][ni] = __builtin_amdgcn_mfma_f32_16x16x32_bf16(af[mi], bfr[ni], acc[mi][ni], 0, 0, 0);
    }
#pragma unroll
    for (int mi = 0; mi < 4; ++mi)
#pragma unroll
        for (int ni = 0; ni < 4; ++ni) {
            int row = m0 + wr * 64 + mi * 16 + g * 4;
            int col = n0 + wc * 64 + ni * 16 + l15;
#pragma unroll
            for (int r = 0; r < 4; ++r) {
                float v = acc[mi][ni][r];
                if constexpr (ROPE) {
                    float partner = __shfl_xor(v, 1);   // pair lane (col^1)
                    if (col < 2560) {
                        int s = (row + r) & (SEQ - 1);
                        int i2 = (col & 127) >> 1;
                        float2 t = trig[s * 64 + i2];
                        v = (col & 1) ? (v * t.x + partner * t.y)
                                      : (v * t.x - partner * t.y);
                    }
                    if (col < 2048) v *= QSCALE_L2E;
                }
                if constexpr (__is_same(OutT, float))
                    C[(size_t)(row + r) * N + col] = v;
                else
                    C[(size_t)(row + r) * N + col] = __float2bfloat16(v);
            }
        }
}

// ------- GEMM BK=64 (gemm2 only, where it measured faster) -------
template <typename OutT>
__global__ __launch_bounds__(256) void gemm_bt64(const bf16* __restrict__ A,
                                                 const bf16* __restrict__ Bt,
                                                 OutT* __restrict__ C, int M, int N, int K) {
    __shared__ bf16 As[128 * 64];
    __shared__ bf16 Bs[128 * 64];
    const int GX = gridDim.x;
    const int nwg = GX * gridDim.y;
    const int lin = blockIdx.y * GX + blockIdx.x;
    const int swz = (lin & 7) * (nwg >> 3) + (lin >> 3);
    const int m0 = (swz / GX) * 128, n0 = (swz % GX) * 128;
    const int tid = threadIdx.x;
    const int wave = tid >> 6, lane = tid & 63;
    const int wr = wave >> 1, wc = wave & 1;
    const int l15 = lane & 15, g = lane >> 4;
    f32x4 acc[4][4] = {};

    const bf16* ga[4];
    const bf16* gb[4];
#pragma unroll
    for (int i = 0; i < 4; ++i) {
        int cidx = tid + 256 * i;
        int r = cidx >> 3, j = cidx & 7;
        int sc = 8 * (j ^ (r & 7));
        ga[i] = A + (size_t)(m0 + r) * K + sc;
        gb[i] = Bt + (size_t)(n0 + r) * K + sc;
    }

    for (int k0 = 0; k0 < K; k0 += 64) {
        __syncthreads();
#pragma unroll
        for (int i = 0; i < 4; ++i) {
            int cidx = tid + 256 * i;
            __builtin_amdgcn_global_load_lds(
                (const __attribute__((address_space(1))) void*)ga[i],
                (__attribute__((address_space(3))) void*)(As + cidx * 8), 16, 0, 0);
            __builtin_amdgcn_global_load_lds(
                (const __attribute__((address_space(1))) void*)gb[i],
                (__attribute__((address_space(3))) void*)(Bs + cidx * 8), 16, 0, 0);
            ga[i] += 64;
            gb[i] += 64;
        }
        __syncthreads();
#pragma unroll
        for (int kk = 0; kk < 2; ++kk) {
            short8 af[4], bfr[4];
#pragma unroll
            for (int mi = 0; mi < 4; ++mi) {
                int row = wr * 64 + mi * 16 + l15;
                af[mi] = *(const short8*)&As[row * 64 + ((kk * 32 + g * 8) ^ ((row & 7) << 3))];
            }
#pragma unroll
            for (int ni = 0; ni < 4; ++ni) {
                int row = wc * 64 + ni * 16 + l15;
                bfr[ni] = *(const short8*)&Bs[row * 64 + ((kk * 32 + g * 8) ^ ((row & 7) << 3))];
            }
#pragma unroll
            for (int mi = 0; mi < 4; ++mi)
#pragma unroll
                for (int ni = 0; ni < 4; ++ni)
                    acc[mi][ni] = __builtin_amdgcn_mfma_f32_16x16x32_bf16(af[mi], bfr[ni], acc[mi][ni], 0, 0, 0);
        }
    }
#pragma unroll
    for (int mi = 0; mi < 4; ++mi)
#pragma unroll
        for (int ni = 0; ni < 4; ++ni) {
            int row = m0 + wr * 64 + mi * 16 + g * 4;
            int col = n0 + wc * 64 + ni * 16 + l15;
#pragma unroll
            for (int r = 0; r < 4; ++r) {
                float v = acc[mi][ni][r];
                if constexpr (__is_same(OutT, float))
                    C[(size_t)(row + r) * N + col] = v;
                else
                    C[(size_t)(row + r) * N + col] = __float2bfloat16(v);
            }
        }
}

// ---- MFMA flash attention v10 (R25/R26, proven): vote defer-max + setprio MFMA clusters ----
#define PL_LD 72
__global__ __launch_bounds__(256) void attn10(const bf16* __restrict__ qkv,
                                              const bf16* __restrict__ vT,
                                              bf16* __restrict__ y) {
    const int bx = blockIdx.x, h = blockIdx.y, b = blockIdx.z;
    const int kvh = h >> 2;
    const int tid = threadIdx.x, wave = tid >> 6, lane = tid & 63;
    const int l15 = lane & 15, g = lane >> 4;
    __shared__ bf16 Ks[64 * 128];
    __shared__ bf16 Vt[128 * 64];
    __shared__ bf16 Pl[4][16 * PL_LD];
    bf16* plw = Pl[0] + wave * 16 * PL_LD;

    for (int half = 0; half < 2; ++half) {
        const int qt = half ? (31 - bx) : bx;
        const int qrow0 = qt * 64 + wave * 16;
        short8 qf[4];
        {
            const bf16* qp = qkv + (size_t)(b * SEQ + qrow0 + l15) * QKV_N + h * HD + g * 8;
#pragma unroll
            for (int c = 0; c < 4; ++c) qf[c] = *(const short8*)(qp + c * 32);
        }
        f32x4 acc[8] = {};
        float m_[4], lsum[4];
#pragma unroll
        for (int r = 0; r < 4; ++r) { m_[r] = -3.0e38f; lsum[r] = 0.f; }

        const bf16* gk[4];
        const bf16* gv[4];
#pragma unroll
        for (int i = 0; i < 4; ++i) {
            int cidx = tid + 256 * i;
            int key = cidx >> 4, j = cidx & 15;
            gk[i] = qkv + (size_t)(b * SEQ + key) * QKV_N + D_MODEL + kvh * HD + 8 * (j ^ (key & 7));
            int d = cidx >> 3, j2 = cidx & 7;
            gv[i] = vT + (size_t)(b * 512 + kvh * HD + d) * 2048 + 8 * (j2 ^ (d & 7));
        }

        const int diag_kv0 = qt * 64;
        for (int kv0 = 0; kv0 <= diag_kv0; kv0 += 64) {
#pragma unroll
            for (int i = 0; i < 4; ++i) {
                int cidx = tid + 256 * i;
                __builtin_amdgcn_global_load_lds(
                    (const __attribute__((address_space(1))) void*)gk[i],
                    (__attribute__((address_space(3))) void*)(Ks + cidx * 8), 16, 0, 0);
                __builtin_amdgcn_global_load_lds(
                    (const __attribute__((address_space(1))) void*)gv[i],
                    (__attribute__((address_space(3))) void*)(Vt + cidx * 8), 16, 0, 0);
                gk[i] += 64 * QKV_N;
                gv[i] += 64;
            }
            __syncthreads();

            f32x4 sc[4];
            __builtin_amdgcn_s_setprio(1);
#pragma unroll
            for (int ct = 0; ct < 4; ++ct) {
                sc[ct] = (f32x4){0.f, 0.f, 0.f, 0.f};
                int key = ct * 16 + l15;
                int ksw = (key & 7) << 3;
#pragma unroll
                for (int c = 0; c < 4; ++c) {
                    short8 kf = *(const short8*)&Ks[key * 128 + ((c * 32 + g * 8) ^ ksw)];
                    sc[ct] = __builtin_amdgcn_mfma_f32_16x16x32_bf16(qf[c], kf, sc[ct], 0, 0, 0);
                }
            }
            __builtin_amdgcn_s_setprio(0);
            if (kv0 == diag_kv0) {
                int qbase = qrow0 + g * 4;
#pragma unroll
                for (int ct = 0; ct < 4; ++ct) {
                    int key = kv0 + ct * 16 + l15;
#pragma unroll
                    for (int r = 0; r < 4; ++r)
                        if (key > qbase + r) sc[ct][r] = -3.0e38f;
                }
            }
#pragma unroll
            for (int r = 0; r < 4; ++r) {
                float pmax = fmaxf(fmaxf(sc[0][r], sc[1][r]), fmaxf(sc[2][r], sc[3][r]));
                if (__any(pmax > m_[r] + 8.0f)) {
                    float mx = pmax;
#pragma unroll
                    for (int o = 1; o < 16; o <<= 1) mx = fmaxf(mx, __shfl_xor(mx, o));
                    float mn = fmaxf(m_[r], mx);
                    float alpha = exp2f(m_[r] - mn);
                    m_[r] = mn;
                    lsum[r] *= alpha;
#pragma unroll
                    for (int nt = 0; nt < 8; ++nt) acc[nt][r] *= alpha;
                }
                float p0 = exp2f(sc[0][r] - m_[r]);
                float p1 = exp2f(sc[1][r] - m_[r]);
                float p2 = exp2f(sc[2][r] - m_[r]);
                float p3 = exp2f(sc[3][r] - m_[r]);
                int row = g * 4 + r;
                plw[row * PL_LD + l15]      = __float2bfloat16(p0);
                plw[row * PL_LD + 16 + l15] = __float2bfloat16(p1);
                plw[row * PL_LD + 32 + l15] = __float2bfloat16(p2);
                plw[row * PL_LD + 48 + l15] = __float2bfloat16(p3);
                lsum[r] += (p0 + p1) + (p2 + p3);
            }
            short8 pf0 = *(const short8*)&plw[l15 * PL_LD + g * 8];
            short8 pf1 = *(const short8*)&plw[l15 * PL_LD + 32 + g * 8];
            __builtin_amdgcn_s_setprio(1);
#pragma unroll
            for (int nt = 0; nt < 8; ++nt) {
                int d = nt * 16 + l15;
                int dsw = (d & 7) << 3;
                short8 vf0 = *(const short8*)&Vt[d * 64 + ((g * 8) ^ dsw)];
                short8 vf1 = *(const short8*)&Vt[d * 64 + ((32 + g * 8) ^ dsw)];
                acc[nt] = __builtin_amdgcn_mfma_f32_16x16x32_bf16(pf0, vf0, acc[nt], 0, 0, 0);
                acc[nt] = __builtin_amdgcn_mfma_f32_16x16x32_bf16(pf1, vf1, acc[nt], 0, 0, 0);
            }
            __builtin_amdgcn_s_setprio(0);
            __syncthreads();
        }
        float linv[4];
#pragma unroll
        for (int r = 0; r < 4; ++r) {
            float ls = lsum[r];
#pragma unroll
            for (int o = 1; o < 16; o <<= 1) ls += __shfl_xor(ls, o);
            linv[r] = 1.0f / ls;
        }
        int qrow = qrow0 + g * 4;
#pragma unroll
        for (int nt = 0; nt < 8; ++nt) {
            int d = nt * 16 + l15;
#pragma unroll
            for (int r = 0; r < 4; ++r)
                y[(size_t)(b * SEQ + qrow + r) * D_MODEL + h * HD + d] =
                    __float2bfloat16(acc[nt][r] * linv[r]);
        }
        __syncthreads();
    }
}

extern "C" void kernel_launch(void* const* d_in, const int* in_sizes, int n_in,
                              void* d_out, int out_size, void* d_ws, size_t ws_size,
                              hipStream_t stream) {
    const float* x  = (const float*)d_in[0];
    const float* wq = (const float*)d_in[1];
    const float* wk = (const float*)d_in[2];
    const float* wv = (const float*)d_in[3];
    const float* wo = (const float*)d_in[4];

    // ws (50.33MB proven): qkvb bf16 [4096][3072] @0 | ybb bf16 [4096][2048] | woT bf16 [2048][2048]
    // d_out (33.55MB scratch): xb bf16 @0 + wqkvT bf16 + trig; vT [1024][2048] after gemm1
    //   (over dead xb); final: gemm2 writes fp32 output over all of d_out.
    bf16*   qkvb  = (bf16*)d_ws;
    bf16*   ybb   = (bf16*)d_ws + (size_t)NTOK * 3072;
    bf16*   woT   = (bf16*)d_ws + (size_t)NTOK * 3072 + (size_t)NTOK * D_MODEL;
    bf16*   xb    = (bf16*)d_out;
    bf16*   wqkvT = (bf16*)d_out + (size_t)NTOK * D_MODEL;
    float2* trig  = (float2*)((bf16*)d_out + (size_t)NTOK * D_MODEL + (size_t)QKV_N * D_MODEL);
    bf16*   vT    = (bf16*)d_out;      // written by vt64 over dead xb after gemm1
    float*  outf  = (float*)d_out;

    // phase 1: converts + trig table
    conv8<<<dim3(NTOK * D_MODEL / (256 * 8)), 256, 0, stream>>>(x, xb, NTOK * D_MODEL / 8);
    ct64<<<dim3(32, 32), 256, 0, stream>>>(wq, wqkvT, 2048, 2048);
    ct64<<<dim3(8, 32), 256, 0, stream>>>(wk, wqkvT + (size_t)2048 * 2048, 2048, 512);
    ct64<<<dim3(8, 32), 256, 0, stream>>>(wv, wqkvT + (size_t)2560 * 2048, 2048, 512);
    ct64<<<dim3(32, 32), 256, 0, stream>>>(wo, woT, 2048, 2048);
    trig_kernel<<<dim3(SEQ * 64 / 256), 256, 0, stream>>>(trig);

    // phase 2: QKV projection (BK=32, swizzled LDS) with fused RoPE + q-prescale -> qkvb
    gemm_bt32<bf16, true><<<dim3(QKV_N / 128, NTOK / 128), 256, 0, stream>>>(
        xb, wqkvT, qkvb, NTOK, QKV_N, D_MODEL, trig);

    // phase 2.5: V^T (over dead xb)
    vt64<<<dim3(8, 32, BATCH), 256, 0, stream>>>(qkvb, vT);

    // phase 3: attention -> ybb (ws)
    attn10<<<dim3(16, NHEADS, BATCH), 256, 0, stream>>>(qkvb, vT, ybb);

    // phase 4: out-projection (BK=64) -> fp32 directly into d_out
    gemm_bt64<float><<<dim3(D_MODEL / 128, NTOK / 128), 256, 0, stream>>>(
        ybb, woT, outf, NTOK, D_MODEL, D_MODEL);
}

// Round 29
// 228.890 us; speedup vs baseline: 1.2632x; 1.0466x over previous
//
#include <hip/hip_runtime.h>
#include <hip/hip_bf16.h>
#include <stdint.h>

typedef __hip_bfloat16 bf16;
typedef __attribute__((ext_vector_type(8))) short short8;
typedef __attribute__((ext_vector_type(4))) float f32x4;

#define D_MODEL 2048
#define NHEADS 16
#define NKV 4
#define HD 128
#define BATCH 2
#define SEQ 2048
#define NTOK (BATCH*SEQ)
#define QKV_N 3072
#define QSCALE 0.08838834764831845f
#define QSCALE_L2E (0.08838834764831845f * 1.4426950408889634f)

// ---------------- trig table: [s][i] -> (cos, sin), double precision ----------------
__global__ __launch_bounds__(256) void trig_kernel(float2* __restrict__ tab) {
    int idx = blockIdx.x * 256 + threadIdx.x;       // < 2048*64
    int s = idx >> 6, i = idx & 63;
    double inv_freq = pow(10000.0, -(double)i / 64.0);
    double sn, cs;
    sincos((double)s * inv_freq, &sn, &cs);
    tab[idx] = make_float2((float)cs, (float)sn);
}

// ---------------- vectorized convert: fp32 -> bf16 (8 el/thread) ----------------
__global__ __launch_bounds__(256) void conv8(const float* __restrict__ in,
                                             bf16* __restrict__ out, int n8) {
    int idx = blockIdx.x * 256 + threadIdx.x;
    if (idx >= n8) return;
    const float4* p = (const float4*)(in + (size_t)idx * 8);
    float4 a = p[0], b = p[1];
    union { short8 v; bf16 e[8]; } u;
    u.e[0] = __float2bfloat16(a.x); u.e[1] = __float2bfloat16(a.y);
    u.e[2] = __float2bfloat16(a.z); u.e[3] = __float2bfloat16(a.w);
    u.e[4] = __float2bfloat16(b.x); u.e[5] = __float2bfloat16(b.y);
    u.e[6] = __float2bfloat16(b.z); u.e[7] = __float2bfloat16(b.w);
    *(short8*)(out + (size_t)idx * 8) = u.v;
}

// ---- fused convert-transpose of ALL weights: fp32 [2048][N] -> bf16 [N][2048] ----
// grid (80, 32): x<32 -> wq; 32..39 -> wk; 40..47 -> wv; 48..79 -> wo. Block-uniform routing.
#define TILE_LD 68
__global__ __launch_bounds__(256) void ct64all(const float* __restrict__ wq,
                                               const float* __restrict__ wk,
                                               const float* __restrict__ wv,
                                               const float* __restrict__ wo,
                                               bf16* __restrict__ wqkvT,
                                               bf16* __restrict__ woT) {
    __shared__ float tile[64 * TILE_LD];
    const int bx = blockIdx.x, k0 = blockIdx.y * 64;
    const float* in;
    bf16* out;
    int N, n0;
    if (bx < 32)      { in = wq; out = wqkvT;                        N = 2048; n0 = bx * 64; }
    else if (bx < 40) { in = wk; out = wqkvT + (size_t)2048 * 2048;  N = 512;  n0 = (bx - 32) * 64; }
    else if (bx < 48) { in = wv; out = wqkvT + (size_t)2560 * 2048;  N = 512;  n0 = (bx - 40) * 64; }
    else              { in = wo; out = woT;                          N = 2048; n0 = (bx - 48) * 64; }
    const int t = threadIdx.x;
#pragma unroll
    for (int i = 0; i < 4; ++i) {
        int idx = t + 256 * i;
        int r = idx >> 4;
        int c4 = (idx & 15) * 4;
        *(float4*)&tile[r * TILE_LD + c4] = *(const float4*)(in + (size_t)(k0 + r) * N + n0 + c4);
    }
    __syncthreads();
#pragma unroll
    for (int i = 0; i < 2; ++i) {
        int idx = t + 256 * i;
        int n = idx >> 3;
        int kc = (idx & 7) * 8;
        union { short8 v; bf16 e[8]; } u;
#pragma unroll
        for (int j = 0; j < 8; ++j) u.e[j] = __float2bfloat16(tile[(kc + j) * TILE_LD + n]);
        *(short8*)(out + (size_t)(n0 + n) * 2048 + k0 + kc) = u.v;
    }
}

// ---- V^T: qkvb v-cols [token][2560+vd] -> vT [(b*512+vd)][s] (bf16, 64x64 LDS tiles) ----
__global__ __launch_bounds__(256) void vt64(const bf16* __restrict__ qkvb,
                                            bf16* __restrict__ vT) {
    __shared__ bf16 tile[64 * 72];
    int vd0 = blockIdx.x * 64, s0 = blockIdx.y * 64, b = blockIdx.z;
    int t = threadIdx.x;
#pragma unroll
    for (int i = 0; i < 2; ++i) {
        int idx = t + 256 * i;
        int r = idx >> 3;
        int c8 = (idx & 7) * 8;
        *(int4*)&tile[r * 72 + c8] =
            *(const int4*)(qkvb + (size_t)(b * SEQ + s0 + r) * QKV_N + 2560 + vd0 + c8);
    }
    __syncthreads();
#pragma unroll
    for (int i = 0; i < 2; ++i) {
        int idx = t + 256 * i;
        int vd = idx >> 3;
        int s8 = (idx & 7) * 8;
        union { short8 v; bf16 e[8]; } u;
#pragma unroll
        for (int j = 0; j < 8; ++j) u.e[j] = tile[(s8 + j) * 72 + vd];
        *(short8*)(vT + (size_t)(b * 512 + vd0 + vd) * 2048 + s0 + s8) = u.v;
    }
}

// ------- GEMM BK=32 + LDS XOR swizzle (2-way banks): m97 structure, fused-RoPE epilogue -------
template <typename OutT, bool ROPE>
__global__ __launch_bounds__(256) void gemm_bt32(const bf16* __restrict__ A,
                                                 const bf16* __restrict__ Bt,
                                                 OutT* __restrict__ C, int M, int N, int K,
                                                 const float2* __restrict__ trig) {
    __shared__ bf16 As[128 * 32];
    __shared__ bf16 Bs[128 * 32];
    const int GX = gridDim.x;
    const int nwg = GX * gridDim.y;
    const int lin = blockIdx.y * GX + blockIdx.x;
    const int swz = (lin & 7) * (nwg >> 3) + (lin >> 3);
    const int m0 = (swz / GX) * 128, n0 = (swz % GX) * 128;
    const int tid = threadIdx.x;
    const int wave = tid >> 6, lane = tid & 63;
    const int wr = wave >> 1, wc = wave & 1;
    const int l15 = lane & 15, g = lane >> 4;
    const int srow = lane >> 2;
    const int sk8 = 8 * ((lane & 3) ^ ((srow >> 1) & 3));
    const int rsw = ((l15 >> 1) & 3) << 3;
    f32x4 acc[4][4] = {};

    for (int k0 = 0; k0 < K; k0 += 32) {
        __syncthreads();
#pragma unroll
        for (int i = 0; i < 2; ++i) {
            int chunk = wave * 2 + i;
            const bf16* ga = A + (size_t)(m0 + chunk * 16 + srow) * K + k0 + sk8;
            bf16* la = As + chunk * 512 + lane * 8;
            __builtin_amdgcn_global_load_lds((const __attribute__((address_space(1))) void*)ga,
                                             (__attribute__((address_space(3))) void*)la, 16, 0, 0);
            const bf16* gb = Bt + (size_t)(n0 + chunk * 16 + srow) * K + k0 + sk8;
            bf16* lb = Bs + chunk * 512 + lane * 8;
            __builtin_amdgcn_global_load_lds((const __attribute__((address_space(1))) void*)gb,
                                             (__attribute__((address_space(3))) void*)lb, 16, 0, 0);
        }
        __syncthreads();
        short8 af[4], bfr[4];
#pragma unroll
        for (int mi = 0; mi < 4; ++mi)
            af[mi] = *(const short8*)&As[(wr * 64 + mi * 16 + l15) * 32 + ((g * 8) ^ rsw)];
#pragma unroll
        for (int ni = 0; ni < 4; ++ni)
            bfr[ni] = *(const short8*)&Bs[(wc * 64 + ni * 16 + l15) * 32 + ((g * 8) ^ rsw)];
#pragma unroll
        for (int mi = 0; mi < 4; ++mi)
#pragma unroll
            for (int ni = 0; ni < 4; ++ni)
                acc[mi][ni] = __builtin_amdgcn_mfma_f32_16x16x32_bf16(af[mi], bfr[ni], acc[mi][ni], 0, 0, 0);
    }
#pragma unroll
    for (int mi = 0; mi < 4; ++mi)
#pragma unroll
        for (int ni = 0; ni < 4; ++ni) {
            int row = m0 + wr * 64 + mi * 16 + g * 4;
            int col = n0 + wc * 64 + ni * 16 + l15;
#pragma unroll
            for (int r = 0; r < 4; ++r) {
                float v = acc[mi][ni][r];
                if constexpr (ROPE) {
                    float partner = __shfl_xor(v, 1);   // pair lane (col^1)
                    if (col < 2560) {
                        int s = (row + r) & (SEQ - 1);
                        int i2 = (col & 127) >> 1;
                        float2 t = trig[s * 64 + i2];
                        v = (col & 1) ? (v * t.x + partner * t.y)
                                      : (v * t.x - partner * t.y);
                    }
                    if (col < 2048) v *= QSCALE_L2E;
                }
                if constexpr (__is_same(OutT, float))
                    C[(size_t)(row + r) * N + col] = v;
                else
                    C[(size_t)(row + r) * N + col] = __float2bfloat16(v);
            }
        }
}

// ------- GEMM BK=64 (gemm2 only, where it measured faster) -------
template <typename OutT>
__global__ __launch_bounds__(256) void gemm_bt64(const bf16* __restrict__ A,
                                                 const bf16* __restrict__ Bt,
                                                 OutT* __restrict__ C, int M, int N, int K) {
    __shared__ bf16 As[128 * 64];
    __shared__ bf16 Bs[128 * 64];
    const int GX = gridDim.x;
    const int nwg = GX * gridDim.y;
    const int lin = blockIdx.y * GX + blockIdx.x;
    const int swz = (lin & 7) * (nwg >> 3) + (lin >> 3);
    const int m0 = (swz / GX) * 128, n0 = (swz % GX) * 128;
    const int tid = threadIdx.x;
    const int wave = tid >> 6, lane = tid & 63;
    const int wr = wave >> 1, wc = wave & 1;
    const int l15 = lane & 15, g = lane >> 4;
    f32x4 acc[4][4] = {};

    const bf16* ga[4];
    const bf16* gb[4];
#pragma unroll
    for (int i = 0; i < 4; ++i) {
        int cidx = tid + 256 * i;
        int r = cidx >> 3, j = cidx & 7;
        int sc = 8 * (j ^ (r & 7));
        ga[i] = A + (size_t)(m0 + r) * K + sc;
        gb[i] = Bt + (size_t)(n0 + r) * K + sc;
    }

    for (int k0 = 0; k0 < K; k0 += 64) {
        __syncthreads();
#pragma unroll
        for (int i = 0; i < 4; ++i) {
            int cidx = tid + 256 * i;
            __builtin_amdgcn_global_load_lds(
                (const __attribute__((address_space(1))) void*)ga[i],
                (__attribute__((address_space(3))) void*)(As + cidx * 8), 16, 0, 0);
            __builtin_amdgcn_global_load_lds(
                (const __attribute__((address_space(1))) void*)gb[i],
                (__attribute__((address_space(3))) void*)(Bs + cidx * 8), 16, 0, 0);
            ga[i] += 64;
            gb[i] += 64;
        }
        __syncthreads();
#pragma unroll
        for (int kk = 0; kk < 2; ++kk) {
            short8 af[4], bfr[4];
#pragma unroll
            for (int mi = 0; mi < 4; ++mi) {
                int row = wr * 64 + mi * 16 + l15;
                af[mi] = *(const short8*)&As[row * 64 + ((kk * 32 + g * 8) ^ ((row & 7) << 3))];
            }
#pragma unroll
            for (int ni = 0; ni < 4; ++ni) {
                int row = wc * 64 + ni * 16 + l15;
                bfr[ni] = *(const short8*)&Bs[row * 64 + ((kk * 32 + g * 8) ^ ((row & 7) << 3))];
            }
#pragma unroll
            for (int mi = 0; mi < 4; ++mi)
#pragma unroll
                for (int ni = 0; ni < 4; ++ni)
                    acc[mi][ni] = __builtin_amdgcn_mfma_f32_16x16x32_bf16(af[mi], bfr[ni], acc[mi][ni], 0, 0, 0);
        }
    }
#pragma unroll
    for (int mi = 0; mi < 4; ++mi)
#pragma unroll
        for (int ni = 0; ni < 4; ++ni) {
            int row = m0 + wr * 64 + mi * 16 + g * 4;
            int col = n0 + wc * 64 + ni * 16 + l15;
#pragma unroll
            for (int r = 0; r < 4; ++r) {
                float v = acc[mi][ni][r];
                if constexpr (__is_same(OutT, float))
                    C[(size_t)(row + r) * N + col] = v;
                else
                    C[(size_t)(row + r) * N + col] = __float2bfloat16(v);
            }
        }
}

// ---- MFMA flash attention v11: attn10 + XCD-locality block remap (one (b,kvh) per XCD) ----
#define PL_LD 72
__global__ __launch_bounds__(256) void attn11(const bf16* __restrict__ qkv,
                                              const bf16* __restrict__ vT,
                                              bf16* __restrict__ y) {
    // linear dispatch id; groups of L%8 land on one XCD (round-robin heuristic).
    const int L = blockIdx.x + 16 * blockIdx.y + 256 * blockIdx.z;
    const int g8 = L & 7, k = L >> 3;
    const int b = g8 >> 2, kvh = g8 & 3;
    const int bx = k & 15;
    const int h = kvh * 4 + ((k >> 4) & 3);
    const int tid = threadIdx.x, wave = tid >> 6, lane = tid & 63;
    const int l15 = lane & 15, g = lane >> 4;
    __shared__ bf16 Ks[64 * 128];
    __shared__ bf16 Vt[128 * 64];
    __shared__ bf16 Pl[4][16 * PL_LD];
    bf16* plw = Pl[0] + wave * 16 * PL_LD;

    for (int half = 0; half < 2; ++half) {
        const int qt = half ? (31 - bx) : bx;
        const int qrow0 = qt * 64 + wave * 16;
        short8 qf[4];
        {
            const bf16* qp = qkv + (size_t)(b * SEQ + qrow0 + l15) * QKV_N + h * HD + g * 8;
#pragma unroll
            for (int c = 0; c < 4; ++c) qf[c] = *(const short8*)(qp + c * 32);
        }
        f32x4 acc[8] = {};
        float m_[4], lsum[4];
#pragma unroll
        for (int r = 0; r < 4; ++r) { m_[r] = -3.0e38f; lsum[r] = 0.f; }

        const bf16* gk[4];
        const bf16* gv[4];
#pragma unroll
        for (int i = 0; i < 4; ++i) {
            int cidx = tid + 256 * i;
            int key = cidx >> 4, j = cidx & 15;
            gk[i] = qkv + (size_t)(b * SEQ + key) * QKV_N + D_MODEL + kvh * HD + 8 * (j ^ (key & 7));
            int d = cidx >> 3, j2 = cidx & 7;
            gv[i] = vT + (size_t)(b * 512 + kvh * HD + d) * 2048 + 8 * (j2 ^ (d & 7));
        }

        const int diag_kv0 = qt * 64;
        for (int kv0 = 0; kv0 <= diag_kv0; kv0 += 64) {
#pragma unroll
            for (int i = 0; i < 4; ++i) {
                int cidx = tid + 256 * i;
                __builtin_amdgcn_global_load_lds(
                    (const __attribute__((address_space(1))) void*)gk[i],
                    (__attribute__((address_space(3))) void*)(Ks + cidx * 8), 16, 0, 0);
                __builtin_amdgcn_global_load_lds(
                    (const __attribute__((address_space(1))) void*)gv[i],
                    (__attribute__((address_space(3))) void*)(Vt + cidx * 8), 16, 0, 0);
                gk[i] += 64 * QKV_N;
                gv[i] += 64;
            }
            __syncthreads();

            f32x4 sc[4];
            __builtin_amdgcn_s_setprio(1);
#pragma unroll
            for (int ct = 0; ct < 4; ++ct) {
                sc[ct] = (f32x4){0.f, 0.f, 0.f, 0.f};
                int key = ct * 16 + l15;
                int ksw = (key & 7) << 3;
#pragma unroll
                for (int c = 0; c < 4; ++c) {
                    short8 kf = *(const short8*)&Ks[key * 128 + ((c * 32 + g * 8) ^ ksw)];
                    sc[ct] = __builtin_amdgcn_mfma_f32_16x16x32_bf16(qf[c], kf, sc[ct], 0, 0, 0);
                }
            }
            __builtin_amdgcn_s_setprio(0);
            if (kv0 == diag_kv0) {
                int qbase = qrow0 + g * 4;
#pragma unroll
                for (int ct = 0; ct < 4; ++ct) {
                    int key = kv0 + ct * 16 + l15;
#pragma unroll
                    for (int r = 0; r < 4; ++r)
                        if (key > qbase + r) sc[ct][r] = -3.0e38f;
                }
            }
#pragma unroll
            for (int r = 0; r < 4; ++r) {
                float pmax = fmaxf(fmaxf(sc[0][r], sc[1][r]), fmaxf(sc[2][r], sc[3][r]));
                if (__any(pmax > m_[r] + 8.0f)) {
                    float mx = pmax;
#pragma unroll
                    for (int o = 1; o < 16; o <<= 1) mx = fmaxf(mx, __shfl_xor(mx, o));
                    float mn = fmaxf(m_[r], mx);
                    float alpha = exp2f(m_[r] - mn);
                    m_[r] = mn;
                    lsum[r] *= alpha;
#pragma unroll
                    for (int nt = 0; nt < 8; ++nt) acc[nt][r] *= alpha;
                }
                float p0 = exp2f(sc[0][r] - m_[r]);
                float p1 = exp2f(sc[1][r] - m_[r]);
                float p2 = exp2f(sc[2][r] - m_[r]);
                float p3 = exp2f(sc[3][r] - m_[r]);
                int row = g * 4 + r;
                plw[row * PL_LD + l15]      = __float2bfloat16(p0);
                plw[row * PL_LD + 16 + l15] = __float2bfloat16(p1);
                plw[row * PL_LD + 32 + l15] = __float2bfloat16(p2);
                plw[row * PL_LD + 48 + l15] = __float2bfloat16(p3);
                lsum[r] += (p0 + p1) + (p2 + p3);
            }
            short8 pf0 = *(const short8*)&plw[l15 * PL_LD + g * 8];
            short8 pf1 = *(const short8*)&plw[l15 * PL_LD + 32 + g * 8];
            __builtin_amdgcn_s_setprio(1);
#pragma unroll
            for (int nt = 0; nt < 8; ++nt) {
                int d = nt * 16 + l15;
                int dsw = (d & 7) << 3;
                short8 vf0 = *(const short8*)&Vt[d * 64 + ((g * 8) ^ dsw)];
                short8 vf1 = *(const short8*)&Vt[d * 64 + ((32 + g * 8) ^ dsw)];
                acc[nt] = __builtin_amdgcn_mfma_f32_16x16x32_bf16(pf0, vf0, acc[nt], 0, 0, 0);
                acc[nt] = __builtin_amdgcn_mfma_f32_16x16x32_bf16(pf1, vf1, acc[nt], 0, 0, 0);
            }
            __builtin_amdgcn_s_setprio(0);
            __syncthreads();
        }
        float linv[4];
#pragma unroll
        for (int r = 0; r < 4; ++r) {
            float ls = lsum[r];
#pragma unroll
            for (int o = 1; o < 16; o <<= 1) ls += __shfl_xor(ls, o);
            linv[r] = 1.0f / ls;
        }
        int qrow = qrow0 + g * 4;
#pragma unroll
        for (int nt = 0; nt < 8; ++nt) {
            int d = nt * 16 + l15;
#pragma unroll
            for (int r = 0; r < 4; ++r)
                y[(size_t)(b * SEQ + qrow + r) * D_MODEL + h * HD + d] =
                    __float2bfloat16(acc[nt][r] * linv[r]);
        }
        __syncthreads();
    }
}

extern "C" void kernel_launch(void* const* d_in, const int* in_sizes, int n_in,
                              void* d_out, int out_size, void* d_ws, size_t ws_size,
                              hipStream_t stream) {
    const float* x  = (const float*)d_in[0];
    const float* wq = (const float*)d_in[1];
    const float* wk = (const float*)d_in[2];
    const float* wv = (const float*)d_in[3];
    const float* wo = (const float*)d_in[4];

    // ws (50.33MB proven): qkvb bf16 [4096][3072] @0 | ybb bf16 [4096][2048] | woT bf16 [2048][2048]
    // d_out (33.55MB scratch): xb bf16 @0 + wqkvT bf16 + trig; vT [1024][2048] after gemm1
    //   (over dead xb); final: gemm2 writes fp32 output over all of d_out.
    bf16*   qkvb  = (bf16*)d_ws;
    bf16*   ybb   = (bf16*)d_ws + (size_t)NTOK * 3072;
    bf16*   woT   = (bf16*)d_ws + (size_t)NTOK * 3072 + (size_t)NTOK * D_MODEL;
    bf16*   xb    = (bf16*)d_out;
    bf16*   wqkvT = (bf16*)d_out + (size_t)NTOK * D_MODEL;
    float2* trig  = (float2*)((bf16*)d_out + (size_t)NTOK * D_MODEL + (size_t)QKV_N * D_MODEL);
    bf16*   vT    = (bf16*)d_out;      // written by vt64 over dead xb after gemm1
    float*  outf  = (float*)d_out;

    // phase 1: converts (x + all weights in one launch) + trig table
    conv8<<<dim3(NTOK * D_MODEL / (256 * 8)), 256, 0, stream>>>(x, xb, NTOK * D_MODEL / 8);
    ct64all<<<dim3(80, 32), 256, 0, stream>>>(wq, wk, wv, wo, wqkvT, woT);
    trig_kernel<<<dim3(SEQ * 64 / 256), 256, 0, stream>>>(trig);

    // phase 2: QKV projection (BK=32, swizzled LDS) with fused RoPE + q-prescale -> qkvb
    gemm_bt32<bf16, true><<<dim3(QKV_N / 128, NTOK / 128), 256, 0, stream>>>(
        xb, wqkvT, qkvb, NTOK, QKV_N, D_MODEL, trig);

    // phase 2.5: V^T (over dead xb)
    vt64<<<dim3(8, 32, BATCH), 256, 0, stream>>>(qkvb, vT);

    // phase 3: attention (XCD-locality remap) -> ybb (ws)
    attn11<<<dim3(16, NHEADS, BATCH), 256, 0, stream>>>(qkvb, vT, ybb);

    // phase 4: out-projection (BK=64) -> fp32 directly into d_out
    gemm_bt64<float><<<dim3(D_MODEL / 128, NTOK / 128), 256, 0, stream>>>(
        ybb, woT, outf, NTOK, D_MODEL, D_MODEL);
}